// Round 3
// baseline (243.826 us; speedup 1.0000x reference)
//
#include <hip/hip_runtime.h>
#include <math.h>

// Sparse 3D max-pool (kernel=stride=2), gather formulation v2.
// Phase A: CSR binning (hist caches seg ids; scan; scatter).
// Phase B: one wave per segment; parallel index load + shfl broadcast +
//          batched independent feature loads (kills the serial latency chain).

#define CHANNELS 64
#define COARSE_RES 64
#define NSEG (COARSE_RES * COARSE_RES * COARSE_RES)  // 262144
#define SCAN_BLOCKS (NSEG / 256)                     // 1024

__global__ void zero_kernel(int* __restrict__ buf, int n) {
    int i = blockIdx.x * blockDim.x + threadIdx.x;
    int stride = gridDim.x * blockDim.x;
    for (; i < n; i += stride) buf[i] = 0;
}

// histogram + cache segment id per point
__global__ void hist_kernel(const int* __restrict__ coords, int* __restrict__ counts,
                            int* __restrict__ segs, int n) {
    int p = blockIdx.x * blockDim.x + threadIdx.x;
    if (p < n) {
        int ci = coords[p * 3 + 0] >> 1;
        int cj = coords[p * 3 + 1] >> 1;
        int ck = coords[p * 3 + 2] >> 1;
        int seg = (ci * COARSE_RES + cj) * COARSE_RES + ck;
        segs[p] = seg;
        atomicAdd(&counts[seg], 1);
    }
}

// Exclusive scan, 256 elements per block; block totals to blocksums.
__global__ void scan_block_kernel(const int* __restrict__ counts, int* __restrict__ offsets,
                                  int* __restrict__ blocksums) {
    __shared__ int tmp[256];
    int tid = threadIdx.x;
    int gid = blockIdx.x * 256 + tid;
    int v = counts[gid];
    tmp[tid] = v;
    __syncthreads();
    for (int d = 1; d < 256; d <<= 1) {
        int t = (tid >= d) ? tmp[tid - d] : 0;
        __syncthreads();
        tmp[tid] += t;
        __syncthreads();
    }
    offsets[gid] = tmp[tid] - v;  // exclusive
    if (tid == 255) blocksums[blockIdx.x] = tmp[255];
}

__global__ void scan_sums_kernel(int* __restrict__ blocksums) {
    __shared__ int tmp[SCAN_BLOCKS];
    int tid = threadIdx.x;
    int v = blocksums[tid];
    tmp[tid] = v;
    __syncthreads();
    for (int d = 1; d < SCAN_BLOCKS; d <<= 1) {
        int t = (tid >= d) ? tmp[tid - d] : 0;
        __syncthreads();
        tmp[tid] += t;
        __syncthreads();
    }
    blocksums[tid] = tmp[tid] - v;
}

__global__ void scan_add_kernel(int* __restrict__ offsets, int* __restrict__ cursor,
                                const int* __restrict__ blocksums) {
    int gid = blockIdx.x * 256 + threadIdx.x;
    int o = offsets[gid] + blocksums[blockIdx.x];
    offsets[gid] = o;
    cursor[gid] = o;
}

__global__ void scatter_kernel(const int* __restrict__ segs, int* __restrict__ cursor,
                               int* __restrict__ indices, int n) {
    int p = blockIdx.x * blockDim.x + threadIdx.x;
    if (p < n) {
        int pos = atomicAdd(&cursor[segs[p]], 1);
        indices[pos] = p;
    }
}

// One wave per segment; lane = channel. Indices loaded in parallel by lanes,
// broadcast with shfl; feature loads batched 4-at-a-time (independent issue).
__global__ void gather_max_kernel(const float* __restrict__ feat,
                                  const int* __restrict__ indices,
                                  const int* __restrict__ offsets,
                                  const int* __restrict__ counts,
                                  float* __restrict__ out) {
    int wave = (blockIdx.x * blockDim.x + threadIdx.x) >> 6;
    int lane = threadIdx.x & 63;
    if (wave >= NSEG) return;
    int beg = offsets[wave];
    int cnt = counts[wave];
    if (cnt == 0) {
        out[wave * CHANNELS + lane] = 0.0f;
        return;
    }
    float m = -INFINITY;
    for (int base = 0; base < cnt; base += 64) {
        int rem = min(cnt - base, 64);
        int idx = (lane < rem) ? indices[beg + base + lane] : 0;
        const float NEG = -INFINITY;
        for (int t = 0; t < rem; t += 4) {
            // clamped broadcasts: duplicate loads for the ragged tail (cache hits)
            int r1 = min(t + 1, rem - 1);
            int r2 = min(t + 2, rem - 1);
            int r3 = min(t + 3, rem - 1);
            int p0 = __shfl(idx, t);
            int p1 = __shfl(idx, r1);
            int p2 = __shfl(idx, r2);
            int p3 = __shfl(idx, r3);
            float f0 = feat[(long)p0 * CHANNELS + lane];
            float f1 = feat[(long)p1 * CHANNELS + lane];
            float f2 = feat[(long)p2 * CHANNELS + lane];
            float f3 = feat[(long)p3 * CHANNELS + lane];
            f1 = (t + 1 < rem) ? f1 : NEG;  // uniform selects
            f2 = (t + 2 < rem) ? f2 : NEG;
            f3 = (t + 3 < rem) ? f3 : NEG;
            m = fmaxf(m, fmaxf(fmaxf(f0, f1), fmaxf(f2, f3)));
        }
    }
    out[wave * CHANNELS + lane] = m;
}

extern "C" void kernel_launch(void* const* d_in, const int* in_sizes, int n_in,
                              void* d_out, int out_size, void* d_ws, size_t ws_size,
                              hipStream_t stream) {
    const float* feat  = (const float*)d_in[0];
    const int* coords  = (const int*)d_in[1];
    int npoints = in_sizes[0] / CHANNELS;  // 1,000,000

    // Workspace (ints): counts | offsets | cursor | blocksums | indices | segs
    int* ws        = (int*)d_ws;
    int* counts    = ws;
    int* offsets   = counts + NSEG;
    int* cursor    = offsets + NSEG;
    int* blocksums = cursor + NSEG;
    int* indices   = blocksums + SCAN_BLOCKS;
    int* segs      = indices + npoints;

    const int BLOCK = 256;
    int grid_pts = (npoints + BLOCK - 1) / BLOCK;

    zero_kernel<<<512, BLOCK, 0, stream>>>(counts, NSEG);
    hist_kernel<<<grid_pts, BLOCK, 0, stream>>>(coords, counts, segs, npoints);
    scan_block_kernel<<<SCAN_BLOCKS, 256, 0, stream>>>(counts, offsets, blocksums);
    scan_sums_kernel<<<1, SCAN_BLOCKS, 0, stream>>>(blocksums);
    scan_add_kernel<<<SCAN_BLOCKS, 256, 0, stream>>>(offsets, cursor, blocksums);
    scatter_kernel<<<grid_pts, BLOCK, 0, stream>>>(segs, cursor, indices, npoints);

    int grid_gather = NSEG / (BLOCK / 64);  // 65536 blocks of 4 waves
    gather_max_kernel<<<grid_gather, BLOCK, 0, stream>>>(feat, indices, offsets, counts, (float*)d_out);
}

// Round 4
// 174.775 us; speedup vs baseline: 1.3951x; 1.3951x over previous
//
#include <hip/hip_runtime.h>
#include <math.h>

// Sparse 3D max-pool (kernel=stride=2), gather v3: fixed-capacity buckets.
// memset(cursor) -> scatter(coords -> bucket indices) -> gather (1 wave/segment,
// 4 feature rows per load instruction) -> overflow CAS cleanup (empty in practice).

#define CHANNELS 64
#define COARSE_RES 64
#define NSEG (COARSE_RES * COARSE_RES * COARSE_RES)  // 262144
#define CAP 16          // bucket capacity; P(cnt>16) ~ 5e-7 per segment at lambda=3.8
#define MAXOVF 65536    // overflow list capacity (entries)

__global__ void scatter_kernel(const int* __restrict__ coords,
                               int* __restrict__ cursor,
                               int* __restrict__ ovf,       // [0]=count, data at +16
                               int* __restrict__ indices,
                               int n) {
    int p = blockIdx.x * blockDim.x + threadIdx.x;
    if (p >= n) return;
    int ci = coords[3 * p + 0] >> 1;
    int cj = coords[3 * p + 1] >> 1;
    int ck = coords[3 * p + 2] >> 1;
    int seg = (ci * COARSE_RES + cj) * COARSE_RES + ck;
    int pos = atomicAdd(&cursor[seg], 1);
    if (pos < CAP) {
        indices[seg * CAP + pos] = p;
    } else {
        int o = atomicAdd(&ovf[0], 1);
        if (o < MAXOVF) {
            ovf[16 + 2 * o + 0] = p;
            ovf[16 + 2 * o + 1] = seg;
        }
    }
}

// One wave per segment. lane = (g,q): g=lane>>4 selects one of 4 points per
// load batch, q=lane&15 selects the float4 channel-quad. One dwordx4 load
// fetches 4 full 256B feature rows. Duplicated (clamped) rows don't change max.
__global__ void gather_max_kernel(const float* __restrict__ feat,
                                  const int* __restrict__ indices,
                                  const int* __restrict__ cursor,
                                  float* __restrict__ out) {
    int wave = (blockIdx.x * blockDim.x + threadIdx.x) >> 6;
    int lane = threadIdx.x & 63;
    int g = lane >> 4;
    int q = lane & 15;
    // two independent loads, no serial dependency between them
    int cnt = cursor[wave];
    int idx = indices[wave * CAP + q];   // lanes 16..63 duplicate the same 64B line
    cnt = min(cnt, CAP);
    float4 m = make_float4(0.f, 0.f, 0.f, 0.f);
    if (cnt > 0) {
        m = make_float4(-INFINITY, -INFINITY, -INFINITY, -INFINITY);
        for (int t = 0; t * 4 < cnt; ++t) {
            int s = min(t * 4 + g, cnt - 1);     // clamp: duplicate of a valid point
            int p = __shfl(idx, s);
            float4 f = reinterpret_cast<const float4*>(feat + (long)p * CHANNELS)[q];
            m.x = fmaxf(m.x, f.x);
            m.y = fmaxf(m.y, f.y);
            m.z = fmaxf(m.z, f.z);
            m.w = fmaxf(m.w, f.w);
        }
        // reduce across the 4 point-groups: lanes ^16 then ^32
        m.x = fmaxf(m.x, __shfl_xor(m.x, 16));
        m.y = fmaxf(m.y, __shfl_xor(m.y, 16));
        m.z = fmaxf(m.z, __shfl_xor(m.z, 16));
        m.w = fmaxf(m.w, __shfl_xor(m.w, 16));
        m.x = fmaxf(m.x, __shfl_xor(m.x, 32));
        m.y = fmaxf(m.y, __shfl_xor(m.y, 32));
        m.z = fmaxf(m.z, __shfl_xor(m.z, 32));
        m.w = fmaxf(m.w, __shfl_xor(m.w, 32));
    }
    if (lane < 16) {
        reinterpret_cast<float4*>(out)[(long)wave * 16 + q] = m;
    }
}

// Exact cleanup for bucket-overflow points (empty for this input). CAS float max.
__global__ void overflow_kernel(const float* __restrict__ feat,
                                const int* __restrict__ ovf,
                                float* __restrict__ out) {
    int n = min(ovf[0], MAXOVF);
    int total = n * CHANNELS;
    int stride = gridDim.x * blockDim.x;
    for (int k = blockIdx.x * blockDim.x + threadIdx.x; k < total; k += stride) {
        int e = k >> 6;
        int c = k & 63;
        int p = ovf[16 + 2 * e + 0];
        int seg = ovf[16 + 2 * e + 1];
        float v = feat[(long)p * CHANNELS + c];
        int* addr = (int*)&out[(long)seg * CHANNELS + c];
        int old = *addr;
        while (__int_as_float(old) < v) {
            int assumed = old;
            old = atomicCAS(addr, assumed, __float_as_int(v));
            if (old == assumed) break;
        }
    }
}

extern "C" void kernel_launch(void* const* d_in, const int* in_sizes, int n_in,
                              void* d_out, int out_size, void* d_ws, size_t ws_size,
                              hipStream_t stream) {
    const float* feat = (const float*)d_in[0];
    const int* coords = (const int*)d_in[1];
    int npoints = in_sizes[0] / CHANNELS;  // 1,000,000

    // ws layout (ints): cursor[NSEG] | ovf[16 + 2*MAXOVF] | indices[NSEG*CAP]
    int* cursor  = (int*)d_ws;
    int* ovf     = cursor + NSEG;
    int* indices = ovf + 16 + 2 * MAXOVF;

    const int BLOCK = 256;

    // zero cursor + overflow counter in one memset (graph-capturable)
    hipMemsetAsync(cursor, 0, (NSEG + 16) * sizeof(int), stream);

    int grid_pts = (npoints + BLOCK - 1) / BLOCK;
    scatter_kernel<<<grid_pts, BLOCK, 0, stream>>>(coords, cursor, ovf, indices, npoints);

    int grid_gather = NSEG / (BLOCK / 64);  // 65536 blocks, 4 waves each
    gather_max_kernel<<<grid_gather, BLOCK, 0, stream>>>(feat, indices, cursor, (float*)d_out);

    overflow_kernel<<<16, BLOCK, 0, stream>>>(feat, ovf, (float*)d_out);
}

// Round 5
// 140.479 us; speedup vs baseline: 1.7357x; 1.2441x over previous
//
#include <hip/hip_runtime.h>
#include <math.h>

// Sparse 3D max-pool (kernel=stride=2), gather v4: strip-per-wave with
// explicit 2-slot software pipeline across segments.
// zero -> bucket scatter -> strip gather (8 segs/wave, ping-pong chunk loads)
// -> overflow CAS cleanup (statistically empty).

#define CHANNELS 64
#define COARSE_RES 64
#define NSEG (COARSE_RES * COARSE_RES * COARSE_RES)  // 262144
#define CAP 16
#define MAXOVF 65536
#define SPW 8  // segments per wave

__global__ void zero_kernel(int* __restrict__ buf, int n) {
    int i = blockIdx.x * blockDim.x + threadIdx.x;
    int stride = gridDim.x * blockDim.x;
    for (; i < n; i += stride) buf[i] = 0;
}

__global__ void scatter_kernel(const int* __restrict__ coords,
                               int* __restrict__ cursor,
                               int* __restrict__ ovf,       // [0]=count, data at +16
                               int* __restrict__ indices,
                               int n) {
    int p = blockIdx.x * blockDim.x + threadIdx.x;
    if (p >= n) return;
    int ci = coords[3 * p + 0] >> 1;
    int cj = coords[3 * p + 1] >> 1;
    int ck = coords[3 * p + 2] >> 1;
    int seg = (ci * COARSE_RES + cj) * COARSE_RES + ck;
    int pos = atomicAdd(&cursor[seg], 1);
    if (pos < CAP) {
        indices[seg * CAP + pos] = p;
    } else {
        int o = atomicAdd(&ovf[0], 1);
        if (o < MAXOVF) {
            ovf[16 + 2 * o + 0] = p;
            ovf[16 + 2 * o + 1] = seg;
        }
    }
}

// One wave per 8 consecutive segments. Counts + all 128 bucket indices are
// preloaded into registers; the flattened point list is consumed in chunks
// of 4 rows (whole wave reads one 256B row per load, lane=channel) with an
// explicit 2-slot (A/B) pipeline so ~8 row-loads stay in flight per wave.
__global__ __launch_bounds__(256) void gather_strip_kernel(
        const float* __restrict__ feat,
        const int* __restrict__ indices,
        const int* __restrict__ cursor,
        float* __restrict__ out) {
    int wave = (blockIdx.x * blockDim.x + threadIdx.x) >> 6;
    int lane = threadIdx.x & 63;
    long segbase = (long)wave * SPW;

    int cnt_l = 0;
    if (lane < SPW) {
        cnt_l = cursor[segbase + lane];
        if (cnt_l > CAP) cnt_l = CAP;
    }
    // 128 indices of the strip: 2 ints per lane, fully coalesced 512B
    int2 idx2 = reinterpret_cast<const int2*>(indices + segbase * CAP)[lane];

    int s = 0, t = 0, cs = 0;
    float m = -INFINITY;

    // advance to next seg with work, flushing zeros for empty segs
    #define SKIP_EMPTIES()                                         \
        for (;;) {                                                 \
            if (s >= SPW) break;                                   \
            cs = __shfl(cnt_l, s);                                 \
            if (cs > 0) break;                                     \
            out[(segbase + s) * CHANNELS + lane] = 0.0f;           \
            ++s;                                                   \
        }

    // fetch bucket index r of current seg s from the preloaded registers
    #define EXTRACT(r, dst) {                                      \
        int lsrc = (s << 3) + ((r) >> 1);                          \
        int lo_ = __shfl(idx2.x, lsrc);                            \
        int hi_ = __shfl(idx2.y, lsrc);                            \
        dst = ((r) & 1) ? hi_ : lo_; }

    // issue one chunk: 4 independent 256B row loads (tail rows clamped ->
    // duplicates, harmless for max, MSHR-merged). Advances the walk.
    #define ISSUE(F0, F1, F2, F3, FLUSH, SEG) {                    \
        int r0_ = t;                                               \
        int r1_ = min(t + 1, cs - 1);                              \
        int r2_ = min(t + 2, cs - 1);                              \
        int r3_ = min(t + 3, cs - 1);                              \
        int p0_, p1_, p2_, p3_;                                    \
        EXTRACT(r0_, p0_); EXTRACT(r1_, p1_);                      \
        EXTRACT(r2_, p2_); EXTRACT(r3_, p3_);                      \
        F0 = feat[(long)p0_ * CHANNELS + lane];                    \
        F1 = feat[(long)p1_ * CHANNELS + lane];                    \
        F2 = feat[(long)p2_ * CHANNELS + lane];                    \
        F3 = feat[(long)p3_ * CHANNELS + lane];                    \
        t += 4;                                                    \
        FLUSH = (t >= cs); SEG = s;                                \
        if (FLUSH) { ++s; t = 0; SKIP_EMPTIES(); } }

    #define CONSUME(F0, F1, F2, F3, FLUSH, SEG) {                  \
        m = fmaxf(m, fmaxf(fmaxf(F0, F1), fmaxf(F2, F3)));         \
        if (FLUSH) {                                               \
            out[(segbase + SEG) * CHANNELS + lane] = m;            \
            m = -INFINITY; } }

    SKIP_EMPTIES();
    float fA0, fA1, fA2, fA3, fB0, fB1, fB2, fB3;
    bool flA = false, flB = false;
    int sgA = 0, sgB = 0;
    bool haveA = false, haveB = false;
    if (s < SPW) { ISSUE(fA0, fA1, fA2, fA3, flA, sgA); haveA = true; }
    if (s < SPW) { ISSUE(fB0, fB1, fB2, fB3, flB, sgB); haveB = true; }
    while (haveA) {
        CONSUME(fA0, fA1, fA2, fA3, flA, sgA); haveA = false;
        if (s < SPW) { ISSUE(fA0, fA1, fA2, fA3, flA, sgA); haveA = true; }
        if (!haveB) { if (!haveA) break; else continue; }
        CONSUME(fB0, fB1, fB2, fB3, flB, sgB); haveB = false;
        if (s < SPW) { ISSUE(fB0, fB1, fB2, fB3, flB, sgB); haveB = true; }
    }
    #undef SKIP_EMPTIES
    #undef EXTRACT
    #undef ISSUE
    #undef CONSUME
}

// Exact cleanup for bucket-overflow points (empty for this input). CAS float max.
__global__ void overflow_kernel(const float* __restrict__ feat,
                                const int* __restrict__ ovf,
                                float* __restrict__ out) {
    int n = min(ovf[0], MAXOVF);
    int total = n * CHANNELS;
    int stride = gridDim.x * blockDim.x;
    for (int k = blockIdx.x * blockDim.x + threadIdx.x; k < total; k += stride) {
        int e = k >> 6;
        int c = k & 63;
        int p = ovf[16 + 2 * e + 0];
        int seg = ovf[16 + 2 * e + 1];
        float v = feat[(long)p * CHANNELS + c];
        int* addr = (int*)&out[(long)seg * CHANNELS + c];
        int old = *addr;
        while (__int_as_float(old) < v) {
            int assumed = old;
            old = atomicCAS(addr, assumed, __float_as_int(v));
            if (old == assumed) break;
        }
    }
}

extern "C" void kernel_launch(void* const* d_in, const int* in_sizes, int n_in,
                              void* d_out, int out_size, void* d_ws, size_t ws_size,
                              hipStream_t stream) {
    const float* feat = (const float*)d_in[0];
    const int* coords = (const int*)d_in[1];
    int npoints = in_sizes[0] / CHANNELS;  // 1,000,000

    // ws layout (ints): cursor[NSEG] | ovf[16 + 2*MAXOVF] | indices[NSEG*CAP]
    int* cursor  = (int*)d_ws;
    int* ovf     = cursor + NSEG;
    int* indices = ovf + 16 + 2 * MAXOVF;

    const int BLOCK = 256;

    zero_kernel<<<512, BLOCK, 0, stream>>>(cursor, NSEG + 16);

    int grid_pts = (npoints + BLOCK - 1) / BLOCK;
    scatter_kernel<<<grid_pts, BLOCK, 0, stream>>>(coords, cursor, ovf, indices, npoints);

    // 8 segs per wave, 4 waves per block -> 32 segs per block
    int grid_gather = NSEG / (SPW * (BLOCK / 64));  // 8192
    gather_strip_kernel<<<grid_gather, BLOCK, 0, stream>>>(feat, indices, cursor, (float*)d_out);

    overflow_kernel<<<16, BLOCK, 0, stream>>>(feat, ovf, (float*)d_out);
}